// Round 8
// baseline (621.573 us; speedup 1.0000x reference)
//
#include <hip/hip_runtime.h>
#include <hip/hip_bf16.h>

#define D 128

typedef __bf16 bf16x8 __attribute__((ext_vector_type(8)));
typedef __bf16 bf16x4 __attribute__((ext_vector_type(4)));
typedef __bf16 bf16x2 __attribute__((ext_vector_type(2)));
typedef float  f32x4  __attribute__((ext_vector_type(4)));
typedef float  f32x2  __attribute__((ext_vector_type(2)));

// ---------------------------------------------------------------------------
// Dtype probe: 1 = bf16-packed, 0 = fp32 (R3-R7 evidence: bf16).
// ---------------------------------------------------------------------------
__global__ void detect_kernel(const unsigned int* __restrict__ w, int* flag)
{
    __shared__ int cnt[256];
    int c = 0;
#pragma unroll
    for (int i = 0; i < 4; ++i) {
        unsigned int v = w[threadIdx.x * 4 + i];
        unsigned int e = (v >> 7) & 0xFF;
        if (e >= 90 && e <= 134) ++c;
    }
    cnt[threadIdx.x] = c;
    __syncthreads();
    for (int s = 128; s > 0; s >>= 1) {
        if (threadIdx.x < s) cnt[threadIdx.x] += cnt[threadIdx.x + s];
        __syncthreads();
    }
    if (threadIdx.x == 0) flag[0] = (cnt[0] > 614) ? 1 : 0;
}

template <int ISBF>
__device__ __forceinline__ bf16x8 ld8(const void* p, size_t elem)
{
    if (ISBF) return *(const bf16x8*)((const __bf16*)p + elem);
    const f32x4* f = (const f32x4*)((const float*)p + elem);
    f32x4 lo = f[0], hi = f[1];
    bf16x8 r;
    r[0] = (__bf16)lo[0]; r[1] = (__bf16)lo[1]; r[2] = (__bf16)lo[2]; r[3] = (__bf16)lo[3];
    r[4] = (__bf16)hi[0]; r[5] = (__bf16)hi[1]; r[6] = (__bf16)hi[2]; r[7] = (__bf16)hi[3];
    return r;
}
template <int ISBF>
__device__ __forceinline__ float ldf(const void* p, size_t elem)
{
    return ISBF ? (float)((const __bf16*)p)[elem] : ((const float*)p)[elem];
}

// ---------------------------------------------------------------------------
// CSR build (verified R4-R7)
// ---------------------------------------------------------------------------
__global__ __launch_bounds__(256) void hist_kernel(
    const int* __restrict__ tgt, int* __restrict__ counts, int E)
{
    int e = blockIdx.x * 256 + threadIdx.x;
    if (e < E) atomicAdd(&counts[tgt[e]], 1);
}

__global__ __launch_bounds__(256) void scan1_kernel(
    const int* __restrict__ counts, int* __restrict__ rowptr,
    int* __restrict__ bsum, int M)
{
    __shared__ int sh[256];
    int base = blockIdx.x * 1024 + threadIdx.x * 4;
    int v[4];
#pragma unroll
    for (int k = 0; k < 4; ++k)
        v[k] = (base + k < M) ? counts[base + k] : 0;
    int tot = v[0] + v[1] + v[2] + v[3];
    sh[threadIdx.x] = tot;
    __syncthreads();
    for (int off = 1; off < 256; off <<= 1) {
        int t = (threadIdx.x >= off) ? sh[threadIdx.x - off] : 0;
        __syncthreads();
        sh[threadIdx.x] += t;
        __syncthreads();
    }
    int run = sh[threadIdx.x] - tot;
#pragma unroll
    for (int k = 0; k < 4; ++k) {
        if (base + k < M) rowptr[base + k] = run;
        run += v[k];
    }
    if (threadIdx.x == 255) bsum[blockIdx.x] = sh[255];
}

__global__ __launch_bounds__(256) void scan2_kernel(
    int* __restrict__ bsum, int* __restrict__ boff, int NB)
{
    __shared__ int sh[256];
    int base = threadIdx.x * 4;
    int v[4];
#pragma unroll
    for (int k = 0; k < 4; ++k)
        v[k] = (base + k < NB) ? bsum[base + k] : 0;
    int tot = v[0] + v[1] + v[2] + v[3];
    sh[threadIdx.x] = tot;
    __syncthreads();
    for (int off = 1; off < 256; off <<= 1) {
        int t = (threadIdx.x >= off) ? sh[threadIdx.x - off] : 0;
        __syncthreads();
        sh[threadIdx.x] += t;
        __syncthreads();
    }
    int run = sh[threadIdx.x] - tot;
#pragma unroll
    for (int k = 0; k < 4; ++k) {
        if (base + k < NB) boff[base + k] = run;
        run += v[k];
    }
}

__global__ __launch_bounds__(256) void scan3_kernel(
    int* __restrict__ rowptr, int* __restrict__ cursor,
    const int* __restrict__ boff, int M, int E)
{
    int b = blockIdx.x;
    int base = b * 1024 + threadIdx.x * 4;
    int o = boff[b];
#pragma unroll
    for (int k = 0; k < 4; ++k) {
        int i = base + k;
        if (i < M) {
            int r = rowptr[i] + o;
            rowptr[i] = r;
            cursor[i] = r;
        }
    }
    if (b == 0 && threadIdx.x == 0) rowptr[M] = E;
}

__global__ __launch_bounds__(256) void scatter_kernel(
    const int* __restrict__ deprel, const int* __restrict__ deparc,
    const int* __restrict__ src, const int* __restrict__ tgt,
    int* __restrict__ cursor, int2* __restrict__ recs, int E)
{
    int e = blockIdx.x * 256 + threadIdx.x;
    if (e >= E) return;
    int g = tgt[e];
    int pos = atomicAdd(&cursor[g], 1);
    recs[pos] = make_int2(src[e], (deprel[e] << 2) | deparc[e]);
}

// ---------------------------------------------------------------------------
// FUSED kernel: per-block (32 target nodes):
//   Phase A: aggregate AG[32][512] (gated per-type inp sums) + BA[32][128]
//            into LDS; gate computed on the fly from inp row (deletes gate
//            kernel + G reads).  16 groups x 16 lanes; 1 edge/group in flight.
//   Phase B: loop t: stage W_t -> 32KB LDS (R7-verified swizzle), MFMA from
//            LDS (af from swizzled AG rows), epilogue adds BA, store out.
// Dynamic LDS: Wsh 32KB + AGsh 32KB + BAsh 8.7KB = 74.2KB -> 2 blocks/CU.
// ---------------------------------------------------------------------------
#define BAST 136   // BA LDS row stride in elems (272B = 17 x 16B slots)

template <int ISBF>
__device__ __forceinline__ void fused_body(
    const void* __restrict__ inp,
    const void* __restrict__ b_in, const void* __restrict__ b_out,
    const void* __restrict__ bg_in, const void* __restrict__ bg_out,
    const void* __restrict__ gv_in, const void* __restrict__ gv_out,
    const void* __restrict__ gv_self, const void* __restrict__ gv_norel,
    const void* __restrict__ W0, const void* __restrict__ W1,
    const void* __restrict__ W2, const void* __restrict__ W3,
    const int* __restrict__ rowptr, const int2* __restrict__ recs,
    void* __restrict__ out, int M)
{
    extern __shared__ __bf16 lds[];
    __bf16* Wsh  = lds;                 // [128][128] swizzled, 32KB (reused per t)
    __bf16* AGsh = lds + 16384;         // [32][512]  swizzled, 32KB
    __bf16* BAsh = lds + 32768;         // [32][BAST] padded,   8.7KB

    const int tid = threadIdx.x;
    const int grp = tid >> 4;           // 0..15
    const int l16 = tid & 15;
    const int dd  = l16 * 8;            // dims dd..dd+8
    const int blk = blockIdx.x * 32;

    // gate vectors -> registers (fp32), lane holds dims dd..dd+8 of each
    float gv[4][8];
    {
        bf16x8 v0 = ld8<ISBF>(gv_in, dd);
        bf16x8 v1 = ld8<ISBF>(gv_out, dd);
        bf16x8 v2 = ld8<ISBF>(gv_self, dd);
        bf16x8 v3 = ld8<ISBF>(gv_norel, dd);
#pragma unroll
        for (int k = 0; k < 8; ++k) {
            gv[0][k] = (float)v0[k]; gv[1][k] = (float)v1[k];
            gv[2][k] = (float)v2[k]; gv[3][k] = (float)v3[k];
        }
    }

    // ---------------- Phase A: aggregate into LDS ----------------
#pragma unroll
    for (int rep = 0; rep < 2; ++rep) {
        const int ln = grp + rep * 16;      // local node 0..31
        const int g  = blk + ln;

        float a[4][8];
#pragma unroll
        for (int t = 0; t < 4; ++t)
#pragma unroll
            for (int k = 0; k < 8; ++k) a[t][k] = 0.f;
        float ba[8];
#pragma unroll
        for (int k = 0; k < 8; ++k) ba[k] = 0.f;

        if (g < M) {
            int beg = rowptr[g], end = rowptr[g + 1];
            for (int i = beg; i < end; ++i) {
                int2 rec = recs[i];              // same addr for 16 lanes
                int t = rec.y & 3, r = rec.y >> 2;
                bf16x8 v = ld8<ISBF>(inp, (size_t)rec.x * D + dd);
                float vf[8];
#pragma unroll
                for (int k = 0; k < 8; ++k) vf[k] = (float)v[k];
                // gate pre-activation: dot(inp_row, gate_vec[t]) over 128 dims
                float s = 0.f;
#pragma unroll
                for (int k = 0; k < 8; ++k) s += vf[k] * gv[t][k];
                s += __shfl_xor(s, 1);
                s += __shfl_xor(s, 2);
                s += __shfl_xor(s, 4);
                s += __shfl_xor(s, 8);
                float bg = 0.f;
                if (t == 0)      bg = ldf<ISBF>(bg_in, r);
                else if (t == 1) bg = ldf<ISBF>(bg_out, r);
                float gate = 1.f / (1.f + __expf(-(s + bg)));

                if (t == 0) {
                    bf16x8 bv = ld8<ISBF>(b_in, (size_t)r * D + dd);
#pragma unroll
                    for (int k = 0; k < 8; ++k) {
                        a[0][k] += vf[k] * gate;
                        ba[k] += (float)bv[k] * gate;
                    }
                } else if (t == 1) {
                    bf16x8 bv = ld8<ISBF>(b_out, (size_t)r * D + dd);
#pragma unroll
                    for (int k = 0; k < 8; ++k) {
                        a[1][k] += vf[k] * gate;
                        ba[k] += (float)bv[k] * gate;
                    }
                } else if (t == 2) {
#pragma unroll
                    for (int k = 0; k < 8; ++k) a[2][k] += vf[k] * gate;
                } else {
#pragma unroll
                    for (int k = 0; k < 8; ++k) a[3][k] += vf[k] * gate;
                }
            }
        }

        // write AG rows (swizzled: 16B slot sp = slot ^ (ln&7)) + BA row
#pragma unroll
        for (int t = 0; t < 4; ++t) {
            int slot = t * 16 + l16;
            int sp = slot ^ (ln & 7);
            bf16x8 w;
#pragma unroll
            for (int k = 0; k < 8; ++k) w[k] = (__bf16)a[t][k];
            *(bf16x8*)(AGsh + ln * 512 + sp * 8) = w;
        }
        bf16x8 wb;
#pragma unroll
        for (int k = 0; k < 8; ++k) wb[k] = (__bf16)ba[k];
        *(bf16x8*)(BAsh + ln * BAST + dd) = wb;
    }
    __syncthreads();

    // ---------------- Phase B: out = AG @ WW^T + BA ----------------
    const int wave = tid >> 6;
    const int lane = tid & 63;
    const int lrow = lane & 15;
    const int kgrp = lane >> 4;
    // wave w handles features {2w,2w+1} x16, both node tiles
    const void* Ws[4] = {W0, W1, W2, W3};

    f32x4 acc[2][2];   // [fi][nt]
#pragma unroll
    for (int i = 0; i < 2; ++i)
#pragma unroll
        for (int j = 0; j < 2; ++j) acc[i][j] = (f32x4){0.f, 0.f, 0.f, 0.f};

    for (int t = 0; t < 4; ++t) {
        const void* W = Ws[t];
#pragma unroll
        for (int i = 0; i < 8; ++i) {
            int slot = tid + 256 * i;       // 2048 16B-slots
            int f = slot >> 4;
            int s = slot & 15;
            int sp = s ^ (f & 7);
            bf16x8 v = ld8<ISBF>(W, (size_t)f * D + s * 8);
            *(bf16x8*)(Wsh + f * 128 + sp * 8) = v;
        }
        __syncthreads();

#pragma unroll
        for (int ks = 0; ks < 4; ++ks) {
            int aslot = t * 16 + ks * 4 + kgrp;
            int ln0 = lrow, ln1 = 16 + lrow;
            bf16x8 af0 = *(const bf16x8*)(AGsh + ln0 * 512 + (aslot ^ (ln0 & 7)) * 8);
            bf16x8 af1 = *(const bf16x8*)(AGsh + ln1 * 512 + (aslot ^ (ln1 & 7)) * 8);
            int wslot = ks * 4 + kgrp;
#pragma unroll
            for (int fi = 0; fi < 2; ++fi) {
                int f = (wave * 2 + fi) * 16 + lrow;
                bf16x8 wf = *(const bf16x8*)(Wsh + f * 128 + ((wslot ^ (f & 7))) * 8);
                acc[fi][0] = __builtin_amdgcn_mfma_f32_16x16x32_bf16(wf, af0, acc[fi][0], 0, 0, 0);
                acc[fi][1] = __builtin_amdgcn_mfma_f32_16x16x32_bf16(wf, af1, acc[fi][1], 0, 0, 0);
            }
        }
        __syncthreads();
    }

    // epilogue: node = col (lrow), features = (wave*2+fi)*16 + kgrp*4 + reg
#pragma unroll
    for (int nt = 0; nt < 2; ++nt) {
        int ln = nt * 16 + lrow;
        int node = blk + ln;
        if (node < M) {
#pragma unroll
            for (int fi = 0; fi < 2; ++fi) {
                int f0 = (wave * 2 + fi) * 16 + kgrp * 4;
                bf16x4 bb = *(const bf16x4*)(BAsh + ln * BAST + f0);
                f32x4 v = acc[fi][nt];
                v[0] += (float)bb[0]; v[1] += (float)bb[1];
                v[2] += (float)bb[2]; v[3] += (float)bb[3];
                if (ISBF) {
                    bf16x4 w4;
                    w4[0] = (__bf16)v[0]; w4[1] = (__bf16)v[1];
                    w4[2] = (__bf16)v[2]; w4[3] = (__bf16)v[3];
                    *(bf16x4*)((__bf16*)out + (size_t)node * D + f0) = w4;
                } else {
                    *(f32x4*)((float*)out + (size_t)node * D + f0) = v;
                }
            }
        }
    }
}

__global__ __launch_bounds__(256) void fused_kernel(
    const void* __restrict__ inp,
    const void* __restrict__ b_in, const void* __restrict__ b_out,
    const void* __restrict__ bg_in, const void* __restrict__ bg_out,
    const void* __restrict__ gv_in, const void* __restrict__ gv_out,
    const void* __restrict__ gv_self, const void* __restrict__ gv_norel,
    const void* __restrict__ W0, const void* __restrict__ W1,
    const void* __restrict__ W2, const void* __restrict__ W3,
    const int* __restrict__ rowptr, const int2* __restrict__ recs,
    void* __restrict__ out, int M, const int* __restrict__ flag)
{
    if (flag[0]) fused_body<1>(inp, b_in, b_out, bg_in, bg_out,
                               gv_in, gv_out, gv_self, gv_norel,
                               W0, W1, W2, W3, rowptr, recs, out, M);
    else         fused_body<0>(inp, b_in, b_out, bg_in, bg_out,
                               gv_in, gv_out, gv_self, gv_norel,
                               W0, W1, W2, W3, rowptr, recs, out, M);
}

__global__ void sentinel_kernel(__bf16* o, int n)
{
    int i = blockIdx.x * blockDim.x + threadIdx.x;
    if (i < n) o[i] = (__bf16)12345.0f;
}

static inline size_t align256(size_t x) { return (x + 255) & ~(size_t)255; }

extern "C" void kernel_launch(void* const* d_in, const int* in_sizes, int n_in,
                              void* d_out, int out_size, void* d_ws, size_t ws_size,
                              hipStream_t stream)
{
    const void* inp       = d_in[0];
    const int*  deprel    = (const int*)d_in[1];
    const int*  deparc    = (const int*)d_in[2];
    const int*  eidx      = (const int*)d_in[3];
    const void* V_in      = d_in[4];
    const void* b_in      = d_in[5];
    const void* V_in_g    = d_in[6];
    const void* b_in_g    = d_in[7];
    const void* V_out     = d_in[8];
    const void* b_out     = d_in[9];
    const void* V_out_g   = d_in[10];
    const void* b_out_g   = d_in[11];
    const void* W_self    = d_in[12];
    const void* W_self_g  = d_in[13];
    const void* W_norel   = d_in[14];
    const void* W_norel_g = d_in[15];

    const int M = in_sizes[0] / D;   // 100000
    const int E = in_sizes[1];       // 600000
    const int* src = eidx;
    const int* tgt = eidx + E;
    const int NB = (M + 1023) / 1024;

    size_t off = 0;
    size_t o_flag   = off; off = align256(off + sizeof(int));
    size_t o_counts = off; off = align256(off + (size_t)M * sizeof(int));
    size_t o_rowptr = off; off = align256(off + (size_t)(M + 1) * sizeof(int));
    size_t o_cursor = off; off = align256(off + (size_t)M * sizeof(int));
    size_t o_bsum   = off; off = align256(off + (size_t)NB * sizeof(int));
    size_t o_boff   = off; off = align256(off + (size_t)NB * sizeof(int));
    size_t o_recs   = off; off = align256(off + (size_t)E * sizeof(int2));

    if (off > ws_size) {
        sentinel_kernel<<<(out_size + 255) / 256, 256, 0, stream>>>(
            (__bf16*)d_out, out_size);
        return;
    }

    int*    flag   = (int*)((char*)d_ws + o_flag);
    int*    counts = (int*)((char*)d_ws + o_counts);
    int*    rowptr = (int*)((char*)d_ws + o_rowptr);
    int*    cursor = (int*)((char*)d_ws + o_cursor);
    int*    bsum   = (int*)((char*)d_ws + o_bsum);
    int*    boff   = (int*)((char*)d_ws + o_boff);
    int2*   recs   = (int2*)((char*)d_ws + o_recs);

    detect_kernel<<<1, 256, 0, stream>>>((const unsigned int*)inp, flag);

    // CSR build
    hipMemsetAsync(counts, 0, (size_t)M * sizeof(int), stream);
    hist_kernel<<<(E + 255) / 256, 256, 0, stream>>>(tgt, counts, E);
    scan1_kernel<<<NB, 256, 0, stream>>>(counts, rowptr, bsum, M);
    scan2_kernel<<<1, 256, 0, stream>>>(bsum, boff, NB);
    scan3_kernel<<<NB, 256, 0, stream>>>(rowptr, cursor, boff, M, E);
    scatter_kernel<<<(E + 255) / 256, 256, 0, stream>>>(deprel, deparc, src, tgt,
                                                        cursor, recs, E);

    // fused aggregate + transform (gate computed inline)
    const size_t lds_bytes = (16384 + 16384 + 32 * BAST) * sizeof(__bf16);
    fused_kernel<<<(M + 31) / 32, 256, lds_bytes, stream>>>(
        inp, b_in, b_out, b_in_g, b_out_g,
        V_in_g, V_out_g, W_self_g, W_norel_g,
        V_in, V_out, W_self, W_norel,
        rowptr, recs, d_out, M, flag);
}